// Round 5
// baseline (136.632 us; speedup 1.0000x reference)
//
#include <hip/hip_runtime.h>

// SNDE: 100-step Euler of  u += (tanh(u@W1+b1)@W2 + b2 - gamma*th*pinv*(1-th^2)*wg) * dt
// R4: 512 blocks x 4 waves (256 thr) x 8 samples -> 2 INDEPENDENT blocks per CU
// (decorrelated barriers hide the chain stalls). Wave w owns GEMM1 N-slice
// [64w,64w+64) == GEMM2 K-slice (same-wave h RAW, no mid-step barrier).
// M=16 MFMA tiles carry 8 real + 8 zero rows; lg<2 guards junk-row LDS traffic.

#define GAMMA 0.1f
#define EPSG  1e-12f

typedef __attribute__((ext_vector_type(8))) short bf16x8;
typedef __attribute__((ext_vector_type(4))) float f32x4;

__device__ __forceinline__ float ftanh(float x) {
    float e = __expf(2.0f * x);
    return 1.0f - 2.0f * __builtin_amdgcn_rcpf(e + 1.0f);
}

__device__ __forceinline__ unsigned int f2bf(float f) {
    unsigned int u = __float_as_uint(f);
    return (u + 0x7fffu + ((u >> 16) & 1u)) >> 16;
}

// LDS-only barrier: order LDS ops without draining vmcnt (out stores float).
#define BARRIER_LGKM() asm volatile("s_waitcnt lgkmcnt(0)\ns_barrier" ::: "memory")

__global__ __launch_bounds__(256, 2) void snde_kernel(
    const float* __restrict__ y0, const float* __restrict__ t,
    const float* __restrict__ W1, const float* __restrict__ b1,
    const float* __restrict__ W2, const float* __restrict__ b2,
    const float* __restrict__ wg, const float* __restrict__ bgp,
    float* __restrict__ out)
{
    __shared__ unsigned short uAs[16 * 64];      // bf16 u A-tile (rows 8-15 zero), swizzled
    __shared__ unsigned short hAs[16 * 256];     // bf16 h A-tile (rows 8-15 zero), swizzled
    __shared__ float          fpart[4][8][68];   // per-wave f partials, real rows only

    const int tid = threadIdx.x;
    const int w   = tid >> 6;   // wave 0..3
    const int l   = tid & 63;
    const int l15 = l & 15;
    const int lg  = l >> 4;
    const int s0g = blockIdx.x * 8;

    // ---------------- weight fragments -> registers (one-time) ----------------
    // GEMM1: h(8x256) = u(8x64) @ W1(64x256). Wave w owns n in [64w, 64w+64).
    bf16x8 B1[4][2];
    #pragma unroll
    for (int nt = 0; nt < 4; ++nt) {
        const int n = w * 64 + nt * 16 + l15;
        #pragma unroll
        for (int kt = 0; kt < 2; ++kt) {
            bf16x8 v;
            #pragma unroll
            for (int j = 0; j < 8; ++j) {
                const int k = kt * 32 + lg * 8 + j;
                v[j] = (short)f2bf(W1[k * 256 + n]);
            }
            B1[nt][kt] = v;
        }
    }
    // GEMM2: f(8x64) = h(8x256) @ W2(256x64). Wave w sums k in [64w, 64w+64).
    bf16x8 B2[2][4];
    #pragma unroll
    for (int kt = 0; kt < 2; ++kt) {
        #pragma unroll
        for (int nt = 0; nt < 4; ++nt) {
            const int n = nt * 16 + l15;
            bf16x8 v;
            #pragma unroll
            for (int j = 0; j < 8; ++j) {
                const int k = w * 64 + kt * 32 + lg * 8 + j;
                v[j] = (short)f2bf(W2[k * 64 + n]);
            }
            B2[kt][nt] = v;
        }
    }

    float b1v[4];
    #pragma unroll
    for (int nt = 0; nt < 4; ++nt) b1v[nt] = b1[w * 64 + nt * 16 + l15];

    // update mapping: thread handles sample sU = tid>>5 (0..7), dims dd..dd+1
    const int sU = tid >> 5;
    const int dd = (tid & 31) * 2;
    const float2 wg2  = *(const float2*)(&wg[dd]);
    const float2 b2v2 = *(const float2*)(&b2[dd]);
    float wsum = wg2.x * wg2.x + wg2.y * wg2.y;
    #pragma unroll
    for (int m = 1; m < 32; m <<= 1) wsum += __shfl_xor(wsum, m, 64);
    const float bg  = bgp[0];
    const float dtv = t[1] - t[0];

    // ---------------- init: zero uAs/hAs (finite junk rows), load u, out[0] ----------------
    ((unsigned int*)uAs)[tid]       = 0u;
    ((unsigned int*)uAs)[tid + 256] = 0u;
    #pragma unroll
    for (int j = 0; j < 8; ++j) ((unsigned int*)hAs)[tid + 256 * j] = 0u;
    __syncthreads();

    float2 uv;
    {
        uv = *(const float2*)(&y0[(size_t)(s0g + sU) * 64 + dd]);
        unsigned int p0 = f2bf(uv.x) | (f2bf(uv.y) << 16);
        unsigned int off = (((unsigned)(sU * 128 + dd * 2)) ^ ((unsigned)sU << 4)) >> 2;
        ((unsigned int*)uAs)[off] = p0;
        *(float2*)(&out[(size_t)(s0g + sU) * 64 + dd]) = uv;
    }
    __syncthreads();

    for (int step = 0; step < 100; ++step) {
        // ---- stabilization coef from register u — overlaps GEMM1/2 ----
        float coef;
        {
            float zp = uv.x * wg2.x + uv.y * wg2.y;
            #pragma unroll
            for (int m = 1; m < 32; m <<= 1) zp += __shfl_xor(zp, m, 64);
            const float th = ftanh(zp + bg);
            const float q  = 1.0f - th * th;
            const float sg = q * q * wsum;
            const float pinv = (fabsf(sg) > EPSG) ? __builtin_amdgcn_rcpf(sg) : 0.0f;
            coef = GAMMA * th * pinv * q;
        }

        // ---- GEMM1: acc1 = u @ W1 + b1 (wave's 64-col N-slice) ----
        bf16x8 A1[2];
        #pragma unroll
        for (int kt = 0; kt < 2; ++kt) {
            unsigned int boff = ((unsigned)(l15 * 128 + (kt * 32 + lg * 8) * 2))
                              ^ ((unsigned)(l15 & 7) << 4);
            A1[kt] = *(const bf16x8*)((const char*)uAs + boff);
        }
        f32x4 acc1[4];
        #pragma unroll
        for (int nt = 0; nt < 4; ++nt) {
            acc1[nt][0] = b1v[nt]; acc1[nt][1] = b1v[nt];
            acc1[nt][2] = b1v[nt]; acc1[nt][3] = b1v[nt];
        }
        #pragma unroll
        for (int nt = 0; nt < 4; ++nt)
            #pragma unroll
            for (int kt = 0; kt < 2; ++kt)
                acc1[nt] = __builtin_amdgcn_mfma_f32_16x16x32_bf16(A1[kt], B1[nt][kt], acc1[nt], 0, 0, 0);

        // ---- tanh + scatter real rows (m<8) of own 64-col stripe ----
        if (lg < 2) {
            #pragma unroll
            for (int nt = 0; nt < 4; ++nt) {
                const int n = w * 64 + nt * 16 + l15;
                #pragma unroll
                for (int i = 0; i < 4; ++i) {
                    const int m = lg * 4 + i;   // 0..7
                    const float th = ftanh(acc1[nt][i]);
                    unsigned int boff = ((unsigned)(m * 512 + n * 2)) ^ ((unsigned)(m & 7) << 4);
                    *(unsigned short*)((char*)hAs + boff) = (unsigned short)f2bf(th);
                }
            }
        }
        // same-wave RAW: wave reads back exactly the columns it wrote

        // ---- GEMM2 partial over wave's K-slice [64w, 64w+64) ----
        bf16x8 A2[2];
        #pragma unroll
        for (int kt = 0; kt < 2; ++kt) {
            const int kb = w * 64 + kt * 32 + lg * 8;
            unsigned int boff = ((unsigned)(l15 * 512 + kb * 2)) ^ ((unsigned)(l15 & 7) << 4);
            A2[kt] = *(const bf16x8*)((const char*)hAs + boff);
        }
        f32x4 acc2[4];
        #pragma unroll
        for (int nt = 0; nt < 4; ++nt) {
            acc2[nt][0] = 0.f; acc2[nt][1] = 0.f; acc2[nt][2] = 0.f; acc2[nt][3] = 0.f;
        }
        #pragma unroll
        for (int nt = 0; nt < 4; ++nt)
            #pragma unroll
            for (int kt = 0; kt < 2; ++kt)
                acc2[nt] = __builtin_amdgcn_mfma_f32_16x16x32_bf16(A2[kt], B2[kt][nt], acc2[nt], 0, 0, 0);

        if (lg < 2) {
            #pragma unroll
            for (int nt = 0; nt < 4; ++nt) {
                const int n = nt * 16 + l15;
                #pragma unroll
                for (int i = 0; i < 4; ++i)
                    fpart[w][lg * 4 + i][n] = acc2[nt][i];
            }
        }
        BARRIER_LGKM();   // fpart visible

        // ---- update: f = sum of 4 partials + b2; Euler with precomputed coef ----
        {
            float2 fs = {0.f, 0.f};
            #pragma unroll
            for (int p = 0; p < 4; ++p) {
                const float2 fp = *(const float2*)(&fpart[p][sU][dd]);
                fs.x += fp.x; fs.y += fp.y;
            }
            float2 un;
            un.x = uv.x + (fs.x + b2v2.x - coef * wg2.x) * dtv;
            un.y = uv.y + (fs.y + b2v2.y - coef * wg2.y) * dtv;
            uv = un;
            unsigned int p0 = f2bf(un.x) | (f2bf(un.y) << 16);
            unsigned int off = (((unsigned)(sU * 128 + dd * 2)) ^ ((unsigned)sU << 4)) >> 2;
            ((unsigned int*)uAs)[off] = p0;
            *(float2*)(&out[(size_t)(step + 1) * (4096 * 64) + (size_t)(s0g + sU) * 64 + dd]) = un;
        }
        BARRIER_LGKM();   // uAs republished
    }
}

extern "C" void kernel_launch(void* const* d_in, const int* in_sizes, int n_in,
                              void* d_out, int out_size, void* d_ws, size_t ws_size,
                              hipStream_t stream) {
    const float* y0 = (const float*)d_in[0];
    const float* t  = (const float*)d_in[1];
    const float* W1 = (const float*)d_in[2];
    const float* b1 = (const float*)d_in[3];
    const float* W2 = (const float*)d_in[4];
    const float* b2 = (const float*)d_in[5];
    const float* wg = (const float*)d_in[6];
    const float* bg = (const float*)d_in[7];
    float* out = (float*)d_out;

    snde_kernel<<<dim3(512), dim3(256), 0, stream>>>(y0, t, W1, b1, W2, b2, wg, bg, out);
}

// Round 6
// 110.372 us; speedup vs baseline: 1.2379x; 1.2379x over previous
//
#include <hip/hip_runtime.h>

// SNDE: 100-step Euler of  u += (tanh(u@W1+b1)@W2 + b2 - gamma*th*pinv*(1-th^2)*wg) * dt
// 256 blocks x 8 waves (512 thr) x 16 samples; bf16 MFMA 16x16x32.
// R5 vs R3: (1) zp = u.wg computed as an extra MFMA column on wave 0 (zs[16] in LDS,
// broadcast-read in update) -> no serial ds_bpermute chain at loop top;
// (2) fpart stored as packed bf16 pairs (dims d and d+16 in one u32): LDS traffic
// for partials halved (64->32 KB/step); (3) bank-spread fpart indexing (<=2-way).

#define GAMMA 0.1f
#define EPSG  1e-12f

typedef __attribute__((ext_vector_type(8))) short bf16x8;
typedef __attribute__((ext_vector_type(4))) float f32x4;

__device__ __forceinline__ float ftanh(float x) {
    float e = __expf(2.0f * x);
    return 1.0f - 2.0f * __builtin_amdgcn_rcpf(e + 1.0f);
}

__device__ __forceinline__ unsigned int f2bf(float f) {
    unsigned int u = __float_as_uint(f);
    return (u + 0x7fffu + ((u >> 16) & 1u)) >> 16;
}

__device__ __forceinline__ float bflo(unsigned int p) {          // low bf16 -> f32
    return __uint_as_float(p << 16);
}
__device__ __forceinline__ float bfhi(unsigned int p) {          // high bf16 -> f32
    return __uint_as_float(p & 0xffff0000u);
}

// LDS-only barrier: order LDS ops without draining vmcnt (out stores float).
#define BARRIER_LGKM() asm volatile("s_waitcnt lgkmcnt(0)\ns_barrier" ::: "memory")

__global__ __launch_bounds__(512, 1) void snde_kernel(
    const float* __restrict__ y0, const float* __restrict__ t,
    const float* __restrict__ W1, const float* __restrict__ b1,
    const float* __restrict__ W2, const float* __restrict__ b2,
    const float* __restrict__ wg, const float* __restrict__ bgp,
    float* __restrict__ out)
{
    __shared__ unsigned short uAs[16 * 64];     // bf16 u A-tile, XOR-swizzled (2 KB)
    __shared__ unsigned short hAs[16 * 256];    // bf16 h A-tile, XOR-swizzled (8 KB)
    __shared__ unsigned int   fpp[8 * 16 * 32]; // packed bf16-pair f partials (16 KB)
    __shared__ float          zs[16];           // zp = u.wg per sample

    const int tid = threadIdx.x;
    const int w   = tid >> 6;   // wave 0..7
    const int l   = tid & 63;
    const int l15 = l & 15;
    const int lg  = l >> 4;
    const int s0g = blockIdx.x * 16;

    // ---------------- weight fragments -> registers (one-time) ----------------
    // GEMM1: h(16x256) = u(16x64) @ W1(64x256). Wave w owns n in [32w, 32w+32).
    bf16x8 B1[2][2];
    #pragma unroll
    for (int nt = 0; nt < 2; ++nt) {
        const int n = w * 32 + nt * 16 + l15;
        #pragma unroll
        for (int kt = 0; kt < 2; ++kt) {
            bf16x8 v;
            #pragma unroll
            for (int j = 0; j < 8; ++j) {
                const int k = kt * 32 + lg * 8 + j;
                v[j] = (short)f2bf(W1[k * 256 + n]);
            }
            B1[nt][kt] = v;
        }
    }
    // GEMM2: f(16x64) = h(16x256) @ W2(256x64). Wave w sums k in [32w, 32w+32).
    bf16x8 B2[4];
    #pragma unroll
    for (int nt = 0; nt < 4; ++nt) {
        const int n = nt * 16 + l15;
        bf16x8 v;
        #pragma unroll
        for (int j = 0; j < 8; ++j) {
            const int k = w * 32 + lg * 8 + j;
            v[j] = (short)f2bf(W2[k * 64 + n]);
        }
        B2[nt] = v;
    }
    // z-column frags: B with wg in column 0 only (wave 0 uses them)
    bf16x8 Bz[2];
    #pragma unroll
    for (int kt = 0; kt < 2; ++kt) {
        bf16x8 v;
        #pragma unroll
        for (int j = 0; j < 8; ++j) {
            const int k = kt * 32 + lg * 8 + j;
            v[j] = (l15 == 0) ? (short)f2bf(wg[k]) : (short)0;
        }
        Bz[kt] = v;
    }

    float b1v[2];
    #pragma unroll
    for (int nt = 0; nt < 2; ++nt) b1v[nt] = b1[w * 32 + nt * 16 + l15];

    // update-phase constants: thread handles sample sU, dims d0 = 32*hi+e, d1 = d0+16
    const int sU = tid >> 5;          // 0..15
    const int q  = tid & 31;
    const int hi = q >> 4;            // 0..1
    const int e  = q & 15;
    const int d0 = 32 * hi + e;
    const int d1 = d0 + 16;
    const float wg_0 = wg[d0], wg_1 = wg[d1];
    const float b2_0 = b2[d0], b2_1 = b2[d1];
    float wsum = wg_0 * wg_0 + wg_1 * wg_1;
    #pragma unroll
    for (int m = 1; m < 32; m <<= 1) wsum += __shfl_xor(wsum, m, 64);
    const float bg  = bgp[0];
    const float dtv = t[1] - t[0];

    // ---------------- init u (registers + bf16 LDS); emit out[0] ----------------
    float uv0 = y0[(size_t)(s0g + sU) * 64 + d0];
    float uv1 = y0[(size_t)(s0g + sU) * 64 + d1];
    {
        unsigned int b0 = ((unsigned)(sU * 128 + d0 * 2)) ^ ((unsigned)(sU & 7) << 4);
        unsigned int b1o = ((unsigned)(sU * 128 + d1 * 2)) ^ ((unsigned)(sU & 7) << 4);
        *(unsigned short*)((char*)uAs + b0)  = (unsigned short)f2bf(uv0);
        *(unsigned short*)((char*)uAs + b1o) = (unsigned short)f2bf(uv1);
        out[(size_t)(s0g + sU) * 64 + d0] = uv0;
        out[(size_t)(s0g + sU) * 64 + d1] = uv1;
    }
    __syncthreads();

    for (int step = 0; step < 100; ++step) {
        // ---- GEMM1: acc1 = u @ W1 + b1 (wave's 32-col N-slice) ----
        bf16x8 A1[2];
        #pragma unroll
        for (int kt = 0; kt < 2; ++kt) {
            unsigned int boff = ((unsigned)(l15 * 128 + (kt * 32 + lg * 8) * 2))
                              ^ ((unsigned)(l15 & 7) << 4);
            A1[kt] = *(const bf16x8*)((const char*)uAs + boff);
        }
        f32x4 acc1[2];
        #pragma unroll
        for (int nt = 0; nt < 2; ++nt) {
            acc1[nt][0] = b1v[nt]; acc1[nt][1] = b1v[nt];
            acc1[nt][2] = b1v[nt]; acc1[nt][3] = b1v[nt];
        }
        #pragma unroll
        for (int nt = 0; nt < 2; ++nt)
            #pragma unroll
            for (int kt = 0; kt < 2; ++kt)
                acc1[nt] = __builtin_amdgcn_mfma_f32_16x16x32_bf16(A1[kt], B1[nt][kt], acc1[nt], 0, 0, 0);

        // ---- wave 0: z-column MFMA (zp = u.wg per sample), write zs ----
        if (w == 0) {
            f32x4 accz = {0.f, 0.f, 0.f, 0.f};
            #pragma unroll
            for (int kt = 0; kt < 2; ++kt)
                accz = __builtin_amdgcn_mfma_f32_16x16x32_bf16(A1[kt], Bz[kt], accz, 0, 0, 0);
            if (l15 == 0) *(f32x4*)(&zs[lg * 4]) = accz;   // samples lg*4..lg*4+3
        }

        // ---- tanh, scatter own 32-col stripe of h (bf16, swizzled) ----
        #pragma unroll
        for (int nt = 0; nt < 2; ++nt) {
            const int n = w * 32 + nt * 16 + l15;
            #pragma unroll
            for (int i = 0; i < 4; ++i) {
                const int m = lg * 4 + i;
                const float th = ftanh(acc1[nt][i]);
                unsigned int boff = ((unsigned)(m * 512 + n * 2)) ^ ((unsigned)(m & 7) << 4);
                *(unsigned short*)((char*)hAs + boff) = (unsigned short)f2bf(th);
            }
        }
        // same-wave RAW on hAs: wave reads back exactly the columns it wrote

        // ---- GEMM2 partial over wave's K-slice [32w, 32w+32) ----
        bf16x8 A2;
        {
            unsigned int boff = ((unsigned)(l15 * 512 + (w * 32 + lg * 8) * 2))
                              ^ ((unsigned)(l15 & 7) << 4);
            A2 = *(const bf16x8*)((const char*)hAs + boff);
        }
        f32x4 acc2[4];
        #pragma unroll
        for (int nt = 0; nt < 4; ++nt) {
            acc2[nt][0] = 0.f; acc2[nt][1] = 0.f; acc2[nt][2] = 0.f; acc2[nt][3] = 0.f;
        }
        #pragma unroll
        for (int nt = 0; nt < 4; ++nt)
            acc2[nt] = __builtin_amdgcn_mfma_f32_16x16x32_bf16(A2, B2[nt], acc2[nt], 0, 0, 0);

        // ---- write f partials as packed bf16 pairs: u32 = (dim n, dim n+16) ----
        // value (nt, i): sample s = lg*4+i, dim = nt*16 + l15.
        // pack nt-pairs (0,1) -> idx l15, (2,3) -> idx 16+l15; bank-spread by s.
        #pragma unroll
        for (int i = 0; i < 4; ++i) {
            const int s = lg * 4 + i;
            const unsigned sw = ((unsigned)(s & 7)) << 2;
            fpp[w * 512 + s * 32 + (((unsigned)l15) ^ sw)] =
                f2bf(acc2[0][i]) | (f2bf(acc2[1][i]) << 16);
            fpp[w * 512 + s * 32 + (((unsigned)(16 + l15)) ^ sw)] =
                f2bf(acc2[2][i]) | (f2bf(acc2[3][i]) << 16);
        }
        BARRIER_LGKM();   // fpp + zs visible

        // ---- update: f = sum of 8 packed partials + b2; coef from zs; Euler ----
        {
            const unsigned idxr = ((unsigned)(hi * 16 + e)) ^ (((unsigned)(sU & 7)) << 2);
            float fs0 = 0.f, fs1 = 0.f;
            #pragma unroll
            for (int p = 0; p < 8; ++p) {
                const unsigned int pk = fpp[p * 512 + sU * 32 + idxr];
                fs0 += bflo(pk);
                fs1 += bfhi(pk);
            }
            const float zp = zs[sU];
            const float th = ftanh(zp + bg);
            const float qq = 1.0f - th * th;
            const float sg = qq * qq * wsum;
            const float pinv = (fabsf(sg) > EPSG) ? __builtin_amdgcn_rcpf(sg) : 0.0f;
            const float coef = GAMMA * th * pinv * qq;     // stable_d = coef * wg_d
            const float un0 = uv0 + (fs0 + b2_0 - coef * wg_0) * dtv;
            const float un1 = uv1 + (fs1 + b2_1 - coef * wg_1) * dtv;
            uv0 = un0; uv1 = un1;
            unsigned int b0 = ((unsigned)(sU * 128 + d0 * 2)) ^ ((unsigned)(sU & 7) << 4);
            unsigned int b1o = ((unsigned)(sU * 128 + d1 * 2)) ^ ((unsigned)(sU & 7) << 4);
            *(unsigned short*)((char*)uAs + b0)  = (unsigned short)f2bf(un0);
            *(unsigned short*)((char*)uAs + b1o) = (unsigned short)f2bf(un1);
            float* orow = &out[(size_t)(step + 1) * (4096 * 64) + (size_t)(s0g + sU) * 64];
            orow[d0] = un0;
            orow[d1] = un1;
        }
        BARRIER_LGKM();   // uAs republished
    }
}

extern "C" void kernel_launch(void* const* d_in, const int* in_sizes, int n_in,
                              void* d_out, int out_size, void* d_ws, size_t ws_size,
                              hipStream_t stream) {
    const float* y0 = (const float*)d_in[0];
    const float* t  = (const float*)d_in[1];
    const float* W1 = (const float*)d_in[2];
    const float* b1 = (const float*)d_in[3];
    const float* W2 = (const float*)d_in[4];
    const float* b2 = (const float*)d_in[5];
    const float* wg = (const float*)d_in[6];
    const float* bg = (const float*)d_in[7];
    float* out = (float*)d_out;

    snde_kernel<<<dim3(256), dim3(512), 0, stream>>>(y0, t, W1, b1, W2, b2, wg, bg, out);
}

// Round 8
// 106.876 us; speedup vs baseline: 1.2784x; 1.0327x over previous
//
#include <hip/hip_runtime.h>
#include <hip/hip_bf16.h>

// SNDE: 100-step Euler of  u += (tanh(u@W1+b1)@W2 + b2 - gamma*th*pinv*(1-th^2)*wg) * dt
// 256 blocks x 8 waves (512 thr) x 16 samples; bf16 MFMA 16x16x32.
// R7 = R6 (pair-packed LDS + k-permuted B-frags + packed cvt) with fixes:
//  (1) explicit lgkmcnt(0)+sched_barrier fence for the same-wave hp RAW
//      (R6's u32-write/short8-read TBAA let the compiler drop the wait -> NaN),
//  (2) __float22bfloat162_rn instead of hand-written v_cvt_pk asm,
//  (3) hp zero-init at entry.

#define GAMMA 0.1f
#define EPSG  1e-12f

typedef __attribute__((ext_vector_type(8))) short bf16x8;
typedef __attribute__((ext_vector_type(4))) float f32x4;

__device__ __forceinline__ float ftanh(float x) {
    float e = __expf(2.0f * x);
    return 1.0f - 2.0f * __builtin_amdgcn_rcpf(e + 1.0f);
}

__device__ __forceinline__ unsigned int f2bf(float f) {
    unsigned int u = __float_as_uint(f);
    return (u + 0x7fffu + ((u >> 16) & 1u)) >> 16;
}

// packed (lo,hi) f32 -> (bf16 lo | bf16 hi << 16), RNE; compiler emits cvt_pk
__device__ __forceinline__ unsigned int pack2(float lo, float hi) {
    union { __hip_bfloat162 h; unsigned int u; } cv;
    cv.h = __float22bfloat162_rn(float2{lo, hi});
    return cv.u;
}

__device__ __forceinline__ float bflo(unsigned int p) { return __uint_as_float(p << 16); }
__device__ __forceinline__ float bfhi(unsigned int p) { return __uint_as_float(p & 0xffff0000u); }

// LDS-only barrier: order LDS ops without draining vmcnt (out stores float).
#define BARRIER_LGKM() asm volatile("s_waitcnt lgkmcnt(0)\ns_barrier" ::: "memory")
// same-wave RAW fence (compiler memory barrier + HW drain + no reordering)
#define FENCE_LDS() do { asm volatile("s_waitcnt lgkmcnt(0)" ::: "memory"); \
                         __builtin_amdgcn_sched_barrier(0); } while (0)

// k-slot permutation shared by packed A-frag reads and B-frag init:
// k(j) = base + lg*4 + (j>>1) + 16*(j&1)
__device__ __forceinline__ int kperm(int lg, int j) {
    return lg * 4 + (j >> 1) + ((j & 1) << 4);
}

__global__ __launch_bounds__(512, 1) void snde_kernel(
    const float* __restrict__ y0, const float* __restrict__ t,
    const float* __restrict__ W1, const float* __restrict__ b1,
    const float* __restrict__ W2, const float* __restrict__ b2,
    const float* __restrict__ wg, const float* __restrict__ bgp,
    float* __restrict__ out)
{
    __shared__ unsigned int uAp[16 * 32];       // packed bf16-pair u tile, swizzled (2 KB)
    __shared__ unsigned int hp[16 * 128];       // packed bf16-pair h tile, swizzled (8 KB)
    __shared__ unsigned int fpp[8 * 16 * 32];   // packed bf16-pair f partials (16 KB)
    __shared__ float        zs[16];             // zp = u.wg per sample

    const int tid = threadIdx.x;
    const int w   = tid >> 6;   // wave 0..7
    const int l   = tid & 63;
    const int l15 = l & 15;
    const int lg  = l >> 4;
    const int s0g = blockIdx.x * 16;

    // ---------------- weight fragments -> registers (permuted k-order) ----------------
    bf16x8 B1[2][2];
    #pragma unroll
    for (int nt = 0; nt < 2; ++nt) {
        const int n = w * 32 + nt * 16 + l15;
        #pragma unroll
        for (int kt = 0; kt < 2; ++kt) {
            bf16x8 v;
            #pragma unroll
            for (int j = 0; j < 8; ++j)
                v[j] = (short)f2bf(W1[(kt * 32 + kperm(lg, j)) * 256 + n]);
            B1[nt][kt] = v;
        }
    }
    bf16x8 B2[4];
    #pragma unroll
    for (int nt = 0; nt < 4; ++nt) {
        const int n = nt * 16 + l15;
        bf16x8 v;
        #pragma unroll
        for (int j = 0; j < 8; ++j)
            v[j] = (short)f2bf(W2[(w * 32 + kperm(lg, j)) * 64 + n]);
        B2[nt] = v;
    }
    bf16x8 Bz[2];
    #pragma unroll
    for (int kt = 0; kt < 2; ++kt) {
        bf16x8 v;
        #pragma unroll
        for (int j = 0; j < 8; ++j)
            v[j] = (l15 == 0) ? (short)f2bf(wg[kt * 32 + kperm(lg, j)]) : (short)0;
        Bz[kt] = v;
    }

    float b1v[2];
    #pragma unroll
    for (int nt = 0; nt < 2; ++nt) b1v[nt] = b1[w * 32 + nt * 16 + l15];

    // update-phase mapping: thread = (sample sU, packed col q): d0=32*(q>>4)+(q&15), d1=d0+16
    const int sU = tid >> 5;          // 0..15
    const int q  = tid & 31;
    const int hi = q >> 4;
    const int e  = q & 15;
    const int d0 = 32 * hi + e;
    const int d1 = d0 + 16;
    const float wg_0 = wg[d0], wg_1 = wg[d1];
    const float b2_0 = b2[d0], b2_1 = b2[d1];
    float wsum = wg_0 * wg_0 + wg_1 * wg_1;
    #pragma unroll
    for (int m = 1; m < 32; m <<= 1) wsum += __shfl_xor(wsum, m, 64);
    const float bg  = bgp[0];
    const float dtv = t[1] - t[0];

    // ---------------- init: zero hp; u -> registers + packed LDS; out[0] ----------------
    #pragma unroll
    for (int j = 0; j < 4; ++j) hp[tid + 512 * j] = 0u;

    float uv0 = y0[(size_t)(s0g + sU) * 64 + d0];
    float uv1 = y0[(size_t)(s0g + sU) * 64 + d1];
    {
        uAp[(unsigned)(sU * 32 + q) ^ (((unsigned)(sU & 7)) << 2)] = pack2(uv0, uv1);
        out[(size_t)(s0g + sU) * 64 + d0] = uv0;
        out[(size_t)(s0g + sU) * 64 + d1] = uv1;
    }
    __syncthreads();

    for (int step = 0; step < 100; ++step) {
        // ---- GEMM1: acc1 = u @ W1 + b1 (wave's 32-col N-slice) ----
        bf16x8 A1[2];
        #pragma unroll
        for (int kt = 0; kt < 2; ++kt) {
            unsigned int boff = ((unsigned)(l15 * 128 + (kt * 16 + lg * 4) * 4))
                              ^ (((unsigned)(l15 & 7)) << 4);
            A1[kt] = *(const bf16x8*)((const char*)uAp + boff);
        }
        f32x4 acc1[2];
        #pragma unroll
        for (int nt = 0; nt < 2; ++nt) {
            acc1[nt][0] = b1v[nt]; acc1[nt][1] = b1v[nt];
            acc1[nt][2] = b1v[nt]; acc1[nt][3] = b1v[nt];
        }
        #pragma unroll
        for (int nt = 0; nt < 2; ++nt)
            #pragma unroll
            for (int kt = 0; kt < 2; ++kt)
                acc1[nt] = __builtin_amdgcn_mfma_f32_16x16x32_bf16(A1[kt], B1[nt][kt], acc1[nt], 0, 0, 0);

        // ---- wave 0: z-column MFMA (zp = u.wg per sample) ----
        if (w == 0) {
            f32x4 accz = {0.f, 0.f, 0.f, 0.f};
            #pragma unroll
            for (int kt = 0; kt < 2; ++kt)
                accz = __builtin_amdgcn_mfma_f32_16x16x32_bf16(A1[kt], Bz[kt], accz, 0, 0, 0);
            if (l15 == 0) *(f32x4*)(&zs[lg * 4]) = accz;
        }

        // ---- tanh + packed h scatter: u32 = (h[m][32w+l15], h[m][32w+16+l15]) ----
        #pragma unroll
        for (int i = 0; i < 4; ++i) {
            const int m = lg * 4 + i;
            const unsigned int pk = pack2(ftanh(acc1[0][i]), ftanh(acc1[1][i]));
            unsigned int boff = ((unsigned)(m * 512 + (w * 16 + l15) * 4))
                              ^ (((unsigned)(m & 7)) << 4);
            *(unsigned int*)((char*)hp + boff) = pk;
        }
        FENCE_LDS();   // same-wave RAW: h writes must complete + not be reordered

        // ---- GEMM2 partial over wave's K-slice [32w, 32w+32) ----
        bf16x8 A2;
        {
            unsigned int boff = ((unsigned)(l15 * 512 + (w * 16 + lg * 4) * 4))
                              ^ (((unsigned)(l15 & 7)) << 4);
            A2 = *(const bf16x8*)((const char*)hp + boff);
        }
        f32x4 acc2[4];
        #pragma unroll
        for (int nt = 0; nt < 4; ++nt) {
            acc2[nt][0] = 0.f; acc2[nt][1] = 0.f; acc2[nt][2] = 0.f; acc2[nt][3] = 0.f;
        }
        #pragma unroll
        for (int nt = 0; nt < 4; ++nt)
            acc2[nt] = __builtin_amdgcn_mfma_f32_16x16x32_bf16(A2, B2[nt], acc2[nt], 0, 0, 0);

        // ---- packed f partials: u32 = (f[s][c], f[s][c+16]), bank-spread by s ----
        #pragma unroll
        for (int i = 0; i < 4; ++i) {
            const int s = lg * 4 + i;
            const unsigned sw = ((unsigned)(s & 7)) << 2;
            const int base = w * 512 + s * 32;
            fpp[base + (((unsigned)l15) ^ sw)]        = pack2(acc2[0][i], acc2[1][i]);
            fpp[base + (((unsigned)(16 + l15)) ^ sw)] = pack2(acc2[2][i], acc2[3][i]);
        }
        BARRIER_LGKM();   // fpp + zs visible

        // ---- update: f = sum of 8 packed partials + b2; coef from zs; Euler ----
        {
            const unsigned idxr = ((unsigned)q) ^ (((unsigned)(sU & 7)) << 2);
            float fs0 = 0.f, fs1 = 0.f;
            #pragma unroll
            for (int p = 0; p < 8; ++p) {
                const unsigned int pk = fpp[p * 512 + sU * 32 + idxr];
                fs0 += bflo(pk);
                fs1 += bfhi(pk);
            }
            const float zp = zs[sU];
            const float th = ftanh(zp + bg);
            const float qq = 1.0f - th * th;
            const float sg = qq * qq * wsum;
            const float pinv = (fabsf(sg) > EPSG) ? __builtin_amdgcn_rcpf(sg) : 0.0f;
            const float coef = GAMMA * th * pinv * qq;     // stable_d = coef * wg_d
            const float un0 = uv0 + (fs0 + b2_0 - coef * wg_0) * dtv;
            const float un1 = uv1 + (fs1 + b2_1 - coef * wg_1) * dtv;
            uv0 = un0; uv1 = un1;
            uAp[(unsigned)(sU * 32 + q) ^ (((unsigned)(sU & 7)) << 2)] = pack2(un0, un1);
            float* orow = &out[(size_t)(step + 1) * (4096 * 64) + (size_t)(s0g + sU) * 64];
            orow[d0] = un0;
            orow[d1] = un1;
        }
        BARRIER_LGKM();   // uAp republished
    }
}

extern "C" void kernel_launch(void* const* d_in, const int* in_sizes, int n_in,
                              void* d_out, int out_size, void* d_ws, size_t ws_size,
                              hipStream_t stream) {
    const float* y0 = (const float*)d_in[0];
    const float* t  = (const float*)d_in[1];
    const float* W1 = (const float*)d_in[2];
    const float* b1 = (const float*)d_in[3];
    const float* W2 = (const float*)d_in[4];
    const float* b2 = (const float*)d_in[5];
    const float* wg = (const float*)d_in[6];
    const float* bg = (const float*)d_in[7];
    float* out = (float*)d_out;

    snde_kernel<<<dim3(256), dim3(512), 0, stream>>>(y0, t, W1, b1, W2, b2, wg, bg, out);
}

// Round 9
// 103.846 us; speedup vs baseline: 1.3157x; 1.0292x over previous
//
#include <hip/hip_runtime.h>
#include <hip/hip_bf16.h>

// SNDE: 100-step Euler of  u += (tanh(u@W1+b1)@W2 + b2 - gamma*th*pinv*(1-th^2)*wg) * dt
// 256 blocks x 8 waves (512 thr) x 16 samples; bf16 MFMA 16x16x32.
// R8: full-K GEMM2 (8 MFMAs from the shared h tile) -> f complete in the update
// lane's registers; the entire fpart cross-wave reduction (write+read+unpack+sum)
// is deleted. u-old lives in registers. Waves 0-3 commit tiles [16w,16w+16);
// waves 4-7 run a duplicate GEMM2 to keep both waves/SIMD busy; wave 4 owns the
// z-column + coef chain (coefs[16] via LDS). Still 2 lgkm-only barriers/step.

#define GAMMA 0.1f
#define EPSG  1e-12f

typedef __attribute__((ext_vector_type(8))) short bf16x8;
typedef __attribute__((ext_vector_type(4))) float f32x4;

__device__ __forceinline__ float ftanh(float x) {
    float e = __expf(2.0f * x);
    return 1.0f - 2.0f * __builtin_amdgcn_rcpf(e + 1.0f);
}

__device__ __forceinline__ unsigned int f2bf(float f) {
    unsigned int u = __float_as_uint(f);
    return (u + 0x7fffu + ((u >> 16) & 1u)) >> 16;
}

// packed (lo,hi) f32 -> (bf16 lo | bf16 hi << 16), RNE; compiler emits cvt_pk
__device__ __forceinline__ unsigned int pack2(float lo, float hi) {
    union { __hip_bfloat162 h; unsigned int u; } cv;
    cv.h = __float22bfloat162_rn(float2{lo, hi});
    return cv.u;
}

// LDS-only barrier: order LDS ops without draining vmcnt (out stores float).
#define BARRIER_LGKM() asm volatile("s_waitcnt lgkmcnt(0)\ns_barrier" ::: "memory")

// k-slot permutation for the packed-pair h layout (pairs (c, c+16) per 32-block):
// k_in_block(j) = lg*4 + (j>>1) + 16*(j&1). Applied identically to A2 reads and
// B2 init, so it cancels.
__device__ __forceinline__ int kperm(int lg, int j) {
    return lg * 4 + (j >> 1) + ((j & 1) << 4);
}

__global__ __launch_bounds__(512, 1) void snde_kernel(
    const float* __restrict__ y0, const float* __restrict__ t,
    const float* __restrict__ W1, const float* __restrict__ b1,
    const float* __restrict__ W2, const float* __restrict__ b2,
    const float* __restrict__ wg, const float* __restrict__ bgp,
    float* __restrict__ out)
{
    __shared__ unsigned short uAs[16 * 64];   // bf16 u tile, natural layout, swizzled (2 KB)
    __shared__ unsigned int   hp[16 * 128];   // packed bf16-pair h tile, swizzled (8 KB)
    __shared__ float          coefs[16];      // per-sample stabilization coef

    const int tid = threadIdx.x;
    const int w   = tid >> 6;   // wave 0..7
    const int l   = tid & 63;
    const int l15 = l & 15;
    const int lg  = l >> 4;
    const int nt  = w & 3;      // GEMM2 output tile (cols 16nt..16nt+15)
    const int s0g = blockIdx.x * 16;

    // ---------------- weight fragments -> registers (one-time) ----------------
    // GEMM1: h(16x256) = u(16x64) @ W1. Wave w owns n in [32w, 32w+32); natural k.
    bf16x8 B1[2][2];
    #pragma unroll
    for (int ntt = 0; ntt < 2; ++ntt) {
        const int n = w * 32 + ntt * 16 + l15;
        #pragma unroll
        for (int kt = 0; kt < 2; ++kt) {
            bf16x8 v;
            #pragma unroll
            for (int j = 0; j < 8; ++j)
                v[j] = (short)f2bf(W1[(kt * 32 + lg * 8 + j) * 256 + n]);
            B1[ntt][kt] = v;
        }
    }
    // GEMM2: f(16x64) = h(16x256) @ W2. Tile nt, FULL K=256; kperm'd k-order.
    bf16x8 B2[8];
    #pragma unroll
    for (int kt = 0; kt < 8; ++kt) {
        const int n = nt * 16 + l15;
        bf16x8 v;
        #pragma unroll
        for (int j = 0; j < 8; ++j)
            v[j] = (short)f2bf(W2[(kt * 32 + kperm(lg, j)) * 64 + n]);
        B2[kt] = v;
    }
    // z-column frags (wave 4): wg in column 0, natural k (uses A1)
    bf16x8 Bz[2];
    #pragma unroll
    for (int kt = 0; kt < 2; ++kt) {
        bf16x8 v;
        #pragma unroll
        for (int j = 0; j < 8; ++j)
            v[j] = (l15 == 0) ? (short)f2bf(wg[kt * 32 + lg * 8 + j]) : (short)0;
        Bz[kt] = v;
    }

    float b1v[2];
    #pragma unroll
    for (int ntt = 0; ntt < 2; ++ntt) b1v[ntt] = b1[w * 32 + ntt * 16 + l15];
    const float b2v = b2[nt * 16 + l15];     // seeds accA (same for all 4 rows)
    const float wgv = wg[nt * 16 + l15];
    float wsum = wg[l] * wg[l];
    #pragma unroll
    for (int m = 1; m < 64; m <<= 1) wsum += __shfl_xor(wsum, m, 64);
    const float bg  = bgp[0];
    const float dtv = t[1] - t[0];

    // ---------------- init: uold regs + uAs (natural, swizzled) + out[0] ----------------
    float uold[4];
    if (w < 4) {
        #pragma unroll
        for (int i = 0; i < 4; ++i) {
            const int s = lg * 4 + i;
            const int c = nt * 16 + l15;
            uold[i] = y0[(size_t)(s0g + s) * 64 + c];
            unsigned int boff = ((unsigned)(s * 128 + c * 2)) ^ (((unsigned)(s & 7)) << 4);
            *(unsigned short*)((char*)uAs + boff) = (unsigned short)f2bf(uold[i]);
            out[(size_t)(s0g + s) * 64 + c] = uold[i];
        }
    }
    __syncthreads();

    for (int step = 0; step < 100; ++step) {
        // ======== phase A: GEMM1 + tanh + packed h publish (+ z/coef on wave 4) ========
        bf16x8 A1[2];
        #pragma unroll
        for (int kt = 0; kt < 2; ++kt) {
            unsigned int boff = ((unsigned)(l15 * 128 + (kt * 32 + lg * 8) * 2))
                              ^ (((unsigned)(l15 & 7)) << 4);
            A1[kt] = *(const bf16x8*)((const char*)uAs + boff);
        }
        f32x4 acc1[2];
        #pragma unroll
        for (int ntt = 0; ntt < 2; ++ntt) {
            acc1[ntt][0] = b1v[ntt]; acc1[ntt][1] = b1v[ntt];
            acc1[ntt][2] = b1v[ntt]; acc1[ntt][3] = b1v[ntt];
        }
        #pragma unroll
        for (int ntt = 0; ntt < 2; ++ntt)
            #pragma unroll
            for (int kt = 0; kt < 2; ++kt)
                acc1[ntt] = __builtin_amdgcn_mfma_f32_16x16x32_bf16(A1[kt], B1[ntt][kt], acc1[ntt], 0, 0, 0);

        if (w == 4) {   // z = u.wg per sample -> coef chain -> coefs[16]
            f32x4 accz = {0.f, 0.f, 0.f, 0.f};
            #pragma unroll
            for (int kt = 0; kt < 2; ++kt)
                accz = __builtin_amdgcn_mfma_f32_16x16x32_bf16(A1[kt], Bz[kt], accz, 0, 0, 0);
            if (l15 == 0) {
                f32x4 cf;
                #pragma unroll
                for (int i = 0; i < 4; ++i) {
                    const float th = ftanh(accz[i] + bg);
                    const float qq = 1.0f - th * th;
                    const float sg = qq * qq * wsum;
                    const float pinv = (fabsf(sg) > EPSG) ? __builtin_amdgcn_rcpf(sg) : 0.0f;
                    cf[i] = GAMMA * th * pinv * qq;
                }
                *(f32x4*)(&coefs[lg * 4]) = cf;
            }
        }

        // packed h scatter: word (row m, w*16+l15) = (h[m][32w+l15], h[m][32w+16+l15])
        #pragma unroll
        for (int i = 0; i < 4; ++i) {
            const int m = lg * 4 + i;
            const unsigned int pk = pack2(ftanh(acc1[0][i]), ftanh(acc1[1][i]));
            unsigned int boff = ((unsigned)(m * 512 + (w * 16 + l15) * 4))
                              ^ (((unsigned)(m & 7)) << 4);
            *(unsigned int*)((char*)hp + boff) = pk;
        }
        BARRIER_LGKM();   // h + coefs visible to all waves

        // ======== phase B: full-K GEMM2 -> f in registers -> in-lane update ========
        bf16x8 A2[8];
        #pragma unroll
        for (int kt = 0; kt < 8; ++kt) {
            unsigned int boff = ((unsigned)(l15 * 512 + (kt * 16 + lg * 4) * 4))
                              ^ (((unsigned)(l15 & 7)) << 4);
            A2[kt] = *(const bf16x8*)((const char*)hp + boff);
        }
        f32x4 accA, accB;
        accA[0] = b2v; accA[1] = b2v; accA[2] = b2v; accA[3] = b2v;
        accB[0] = 0.f; accB[1] = 0.f; accB[2] = 0.f; accB[3] = 0.f;
        #pragma unroll
        for (int kt = 0; kt < 4; ++kt)
            accA = __builtin_amdgcn_mfma_f32_16x16x32_bf16(A2[kt], B2[kt], accA, 0, 0, 0);
        #pragma unroll
        for (int kt = 4; kt < 8; ++kt)
            accB = __builtin_amdgcn_mfma_f32_16x16x32_bf16(A2[kt], B2[kt], accB, 0, 0, 0);
        // keep duplicate waves' GEMM2 live (don't let the compiler sink it into w<4)
        asm volatile("" :: "v"(accA[0]), "v"(accA[1]), "v"(accA[2]), "v"(accA[3]),
                           "v"(accB[0]), "v"(accB[1]), "v"(accB[2]), "v"(accB[3]));

        if (w < 4) {
            const f32x4 cf = *(const f32x4*)(&coefs[lg * 4]);
            const int c = nt * 16 + l15;
            float* orow = &out[(size_t)(step + 1) * (4096 * 64) + (size_t)(s0g + lg * 4) * 64 + c];
            #pragma unroll
            for (int i = 0; i < 4; ++i) {
                const float f  = accA[i] + accB[i];
                const float un = uold[i] + (f - cf[i] * wgv) * dtv;
                uold[i] = un;
                const int s = lg * 4 + i;
                unsigned int boff = ((unsigned)(s * 128 + c * 2)) ^ (((unsigned)(s & 7)) << 4);
                *(unsigned short*)((char*)uAs + boff) = (unsigned short)f2bf(un);
                orow[i * 64] = un;
            }
        }
        BARRIER_LGKM();   // uAs republished
    }
}

extern "C" void kernel_launch(void* const* d_in, const int* in_sizes, int n_in,
                              void* d_out, int out_size, void* d_ws, size_t ws_size,
                              hipStream_t stream) {
    const float* y0 = (const float*)d_in[0];
    const float* t  = (const float*)d_in[1];
    const float* W1 = (const float*)d_in[2];
    const float* b1 = (const float*)d_in[3];
    const float* W2 = (const float*)d_in[4];
    const float* b2 = (const float*)d_in[5];
    const float* wg = (const float*)d_in[6];
    const float* bg = (const float*)d_in[7];
    float* out = (float*)d_out;

    snde_kernel<<<dim3(256), dim3(512), 0, stream>>>(y0, t, W1, b1, W2, b2, wg, bg, out);
}

// Round 10
// 94.195 us; speedup vs baseline: 1.4505x; 1.1025x over previous
//
#include <hip/hip_runtime.h>
#include <hip/hip_bf16.h>

// SNDE: 100-step Euler of  u += (tanh(u@W1+b1)@W2 + b2 - gamma*th*pinv*(1-th^2)*wg) * dt
// 256 blocks x 8 waves (512 thr) x 16 samples; bf16 MFMA 16x16x32.
// R9 = R8 with: (1) duplicate GEMM2 on waves 4-7 DELETED (was 32 KB/step of pure
// LDS-port waste; they branch to barrier 2), (2) GEMM2 uses 4 independent
// accumulator chains (2 MFMAs each) instead of 2x4-deep.

#define GAMMA 0.1f
#define EPSG  1e-12f

typedef __attribute__((ext_vector_type(8))) short bf16x8;
typedef __attribute__((ext_vector_type(4))) float f32x4;

__device__ __forceinline__ float ftanh(float x) {
    float e = __expf(2.0f * x);
    return 1.0f - 2.0f * __builtin_amdgcn_rcpf(e + 1.0f);
}

__device__ __forceinline__ unsigned int f2bf(float f) {
    unsigned int u = __float_as_uint(f);
    return (u + 0x7fffu + ((u >> 16) & 1u)) >> 16;
}

// packed (lo,hi) f32 -> (bf16 lo | bf16 hi << 16), RNE; compiler emits cvt_pk
__device__ __forceinline__ unsigned int pack2(float lo, float hi) {
    union { __hip_bfloat162 h; unsigned int u; } cv;
    cv.h = __float22bfloat162_rn(float2{lo, hi});
    return cv.u;
}

// LDS-only barrier: order LDS ops without draining vmcnt (out stores float).
#define BARRIER_LGKM() asm volatile("s_waitcnt lgkmcnt(0)\ns_barrier" ::: "memory")

// k-slot permutation for the packed-pair h layout (pairs (c, c+16) per 32-block):
// applied identically to A2 reads and B2 init, so it cancels.
__device__ __forceinline__ int kperm(int lg, int j) {
    return lg * 4 + (j >> 1) + ((j & 1) << 4);
}

__global__ __launch_bounds__(512, 1) void snde_kernel(
    const float* __restrict__ y0, const float* __restrict__ t,
    const float* __restrict__ W1, const float* __restrict__ b1,
    const float* __restrict__ W2, const float* __restrict__ b2,
    const float* __restrict__ wg, const float* __restrict__ bgp,
    float* __restrict__ out)
{
    __shared__ unsigned short uAs[16 * 64];   // bf16 u tile, natural layout, swizzled (2 KB)
    __shared__ unsigned int   hp[16 * 128];   // packed bf16-pair h tile, swizzled (8 KB)
    __shared__ float          coefs[16];      // per-sample stabilization coef

    const int tid = threadIdx.x;
    const int w   = tid >> 6;   // wave 0..7
    const int l   = tid & 63;
    const int l15 = l & 15;
    const int lg  = l >> 4;
    const int nt  = w & 3;      // GEMM2 output tile (cols 16nt..16nt+15), waves 0-3
    const int s0g = blockIdx.x * 16;

    // ---------------- weight fragments -> registers (one-time) ----------------
    // GEMM1: h(16x256) = u(16x64) @ W1. Wave w owns n in [32w, 32w+32); natural k.
    bf16x8 B1[2][2];
    #pragma unroll
    for (int ntt = 0; ntt < 2; ++ntt) {
        const int n = w * 32 + ntt * 16 + l15;
        #pragma unroll
        for (int kt = 0; kt < 2; ++kt) {
            bf16x8 v;
            #pragma unroll
            for (int j = 0; j < 8; ++j)
                v[j] = (short)f2bf(W1[(kt * 32 + lg * 8 + j) * 256 + n]);
            B1[ntt][kt] = v;
        }
    }
    // GEMM2: f(16x64) = h(16x256) @ W2. Tile nt, FULL K=256; kperm'd k-order.
    bf16x8 B2[8];
    #pragma unroll
    for (int kt = 0; kt < 8; ++kt) {
        const int n = nt * 16 + l15;
        bf16x8 v;
        #pragma unroll
        for (int j = 0; j < 8; ++j)
            v[j] = (short)f2bf(W2[(kt * 32 + kperm(lg, j)) * 64 + n]);
        B2[kt] = v;
    }
    // z-column frags (wave 4): wg in column 0, natural k (uses A1)
    bf16x8 Bz[2];
    #pragma unroll
    for (int kt = 0; kt < 2; ++kt) {
        bf16x8 v;
        #pragma unroll
        for (int j = 0; j < 8; ++j)
            v[j] = (l15 == 0) ? (short)f2bf(wg[kt * 32 + lg * 8 + j]) : (short)0;
        Bz[kt] = v;
    }

    float b1v[2];
    #pragma unroll
    for (int ntt = 0; ntt < 2; ++ntt) b1v[ntt] = b1[w * 32 + ntt * 16 + l15];
    const float b2v = b2[nt * 16 + l15];     // seeds accA (same for all 4 rows)
    const float wgv = wg[nt * 16 + l15];
    float wsum = wg[l] * wg[l];
    #pragma unroll
    for (int m = 1; m < 64; m <<= 1) wsum += __shfl_xor(wsum, m, 64);
    const float bg  = bgp[0];
    const float dtv = t[1] - t[0];

    // ---------------- init: uold regs + uAs (natural, swizzled) + out[0] ----------------
    float uold[4];
    if (w < 4) {
        #pragma unroll
        for (int i = 0; i < 4; ++i) {
            const int s = lg * 4 + i;
            const int c = nt * 16 + l15;
            uold[i] = y0[(size_t)(s0g + s) * 64 + c];
            unsigned int boff = ((unsigned)(s * 128 + c * 2)) ^ (((unsigned)(s & 7)) << 4);
            *(unsigned short*)((char*)uAs + boff) = (unsigned short)f2bf(uold[i]);
            out[(size_t)(s0g + s) * 64 + c] = uold[i];
        }
    }
    __syncthreads();

    for (int step = 0; step < 100; ++step) {
        // ======== phase A: GEMM1 + tanh + packed h publish (+ z/coef on wave 4) ========
        bf16x8 A1[2];
        #pragma unroll
        for (int kt = 0; kt < 2; ++kt) {
            unsigned int boff = ((unsigned)(l15 * 128 + (kt * 32 + lg * 8) * 2))
                              ^ (((unsigned)(l15 & 7)) << 4);
            A1[kt] = *(const bf16x8*)((const char*)uAs + boff);
        }
        f32x4 acc1[2];
        #pragma unroll
        for (int ntt = 0; ntt < 2; ++ntt) {
            acc1[ntt][0] = b1v[ntt]; acc1[ntt][1] = b1v[ntt];
            acc1[ntt][2] = b1v[ntt]; acc1[ntt][3] = b1v[ntt];
        }
        #pragma unroll
        for (int ntt = 0; ntt < 2; ++ntt)
            #pragma unroll
            for (int kt = 0; kt < 2; ++kt)
                acc1[ntt] = __builtin_amdgcn_mfma_f32_16x16x32_bf16(A1[kt], B1[ntt][kt], acc1[ntt], 0, 0, 0);

        if (w == 4) {   // z = u.wg per sample -> coef chain -> coefs[16]
            f32x4 accz = {0.f, 0.f, 0.f, 0.f};
            #pragma unroll
            for (int kt = 0; kt < 2; ++kt)
                accz = __builtin_amdgcn_mfma_f32_16x16x32_bf16(A1[kt], Bz[kt], accz, 0, 0, 0);
            if (l15 == 0) {
                f32x4 cf;
                #pragma unroll
                for (int i = 0; i < 4; ++i) {
                    const float th = ftanh(accz[i] + bg);
                    const float qq = 1.0f - th * th;
                    const float sg = qq * qq * wsum;
                    const float pinv = (fabsf(sg) > EPSG) ? __builtin_amdgcn_rcpf(sg) : 0.0f;
                    cf[i] = GAMMA * th * pinv * qq;
                }
                *(f32x4*)(&coefs[lg * 4]) = cf;
            }
        }

        // packed h scatter: word (row m, w*16+l15) = (h[m][32w+l15], h[m][32w+16+l15])
        #pragma unroll
        for (int i = 0; i < 4; ++i) {
            const int m = lg * 4 + i;
            const unsigned int pk = pack2(ftanh(acc1[0][i]), ftanh(acc1[1][i]));
            unsigned int boff = ((unsigned)(m * 512 + (w * 16 + l15) * 4))
                              ^ (((unsigned)(m & 7)) << 4);
            *(unsigned int*)((char*)hp + boff) = pk;
        }
        BARRIER_LGKM();   // h + coefs visible to all waves

        // ======== phase B (waves 0-3 only): full-K GEMM2 -> in-lane update ========
        if (w < 4) {
            bf16x8 A2[8];
            #pragma unroll
            for (int kt = 0; kt < 8; ++kt) {
                unsigned int boff = ((unsigned)(l15 * 512 + (kt * 16 + lg * 4) * 4))
                                  ^ (((unsigned)(l15 & 7)) << 4);
                A2[kt] = *(const bf16x8*)((const char*)hp + boff);
            }
            // 4 independent 2-deep accumulator chains
            f32x4 accA, accB, accC, accD;
            accA[0] = b2v; accA[1] = b2v; accA[2] = b2v; accA[3] = b2v;
            accB[0] = 0.f; accB[1] = 0.f; accB[2] = 0.f; accB[3] = 0.f;
            accC = accB; accD = accB;
            accA = __builtin_amdgcn_mfma_f32_16x16x32_bf16(A2[0], B2[0], accA, 0, 0, 0);
            accB = __builtin_amdgcn_mfma_f32_16x16x32_bf16(A2[1], B2[1], accB, 0, 0, 0);
            accC = __builtin_amdgcn_mfma_f32_16x16x32_bf16(A2[2], B2[2], accC, 0, 0, 0);
            accD = __builtin_amdgcn_mfma_f32_16x16x32_bf16(A2[3], B2[3], accD, 0, 0, 0);
            accA = __builtin_amdgcn_mfma_f32_16x16x32_bf16(A2[4], B2[4], accA, 0, 0, 0);
            accB = __builtin_amdgcn_mfma_f32_16x16x32_bf16(A2[5], B2[5], accB, 0, 0, 0);
            accC = __builtin_amdgcn_mfma_f32_16x16x32_bf16(A2[6], B2[6], accC, 0, 0, 0);
            accD = __builtin_amdgcn_mfma_f32_16x16x32_bf16(A2[7], B2[7], accD, 0, 0, 0);

            const f32x4 cf = *(const f32x4*)(&coefs[lg * 4]);
            const int c = nt * 16 + l15;
            float* orow = &out[(size_t)(step + 1) * (4096 * 64) + (size_t)(s0g + lg * 4) * 64 + c];
            #pragma unroll
            for (int i = 0; i < 4; ++i) {
                const float f  = (accA[i] + accB[i]) + (accC[i] + accD[i]);
                const float un = uold[i] + (f - cf[i] * wgv) * dtv;
                uold[i] = un;
                const int s = lg * 4 + i;
                unsigned int boff = ((unsigned)(s * 128 + c * 2)) ^ (((unsigned)(s & 7)) << 4);
                *(unsigned short*)((char*)uAs + boff) = (unsigned short)f2bf(un);
                orow[i * 64] = un;
            }
        }
        BARRIER_LGKM();   // uAs republished
    }
}

extern "C" void kernel_launch(void* const* d_in, const int* in_sizes, int n_in,
                              void* d_out, int out_size, void* d_ws, size_t ws_size,
                              hipStream_t stream) {
    const float* y0 = (const float*)d_in[0];
    const float* t  = (const float*)d_in[1];
    const float* W1 = (const float*)d_in[2];
    const float* b1 = (const float*)d_in[3];
    const float* W2 = (const float*)d_in[4];
    const float* b2 = (const float*)d_in[5];
    const float* wg = (const float*)d_in[6];
    const float* bg = (const float*)d_in[7];
    float* out = (float*)d_out;

    snde_kernel<<<dim3(256), dim3(512), 0, stream>>>(y0, t, W1, b1, W2, b2, wg, bg, out);
}